// Round 13
// baseline (158.822 us; speedup 1.0000x reference)
//
#include <hip/hip_runtime.h>
#include <hip/hip_bf16.h>
#include <stdint.h>

#define B_ROWS 32768
#define DIM 512
#define THREADS 256
#define NKT 32              // K-steps of 32 over K=1024
#define ASLOT 16384         // 128 rows x 128 B fp32, one A slot
#define LDS_TOTAL (3 * ASLOT)   // 48 KB -> 2 blocks/CU easily

typedef __attribute__((ext_vector_type(8))) __bf16 bf16x8;
typedef __attribute__((ext_vector_type(4))) float f32x4;
typedef __attribute__((ext_vector_type(4))) unsigned int uint4v;

__device__ static inline unsigned short f2bf(float f) {
    unsigned int u = __builtin_bit_cast(unsigned int, f);
    u += 0x7fffu + ((u >> 16) & 1u);
    return (unsigned short)(u >> 16);
}

__device__ static inline void load_lds_16B(const void* g, void* lds) {
    __builtin_amdgcn_global_load_lds(
        (const __attribute__((address_space(1))) unsigned int*)g,
        (__attribute__((address_space(3))) unsigned int*)lds,
        16, 0, 0);
}

// Wt2[kt 0..31][t 0..2][n 0..511][64B], PLAIN layout (no XOR): byte = kc*2.
// Consumed by direct global->reg reads (1 KB contiguous per wave-instr).
__global__ void prep_weights(const float* __restrict__ Wu_x, const float* __restrict__ Wu_h,
                             const float* __restrict__ Wr_x, const float* __restrict__ Wr_h,
                             const float* __restrict__ Wc_x, const float* __restrict__ Wc_h,
                             unsigned short* __restrict__ Wt2) {
    __shared__ float tile[32][33];
    const int t = blockIdx.z;
    const int k0 = blockIdx.x * 32;
    const int n0 = blockIdx.y * 32;
    const float* Wx = (t == 0) ? Wu_x : (t == 1) ? Wr_x : Wc_x;
    const float* Wh = (t == 0) ? Wu_h : (t == 1) ? Wr_h : Wc_h;
    const int tid = threadIdx.x;
    const int c = tid & 31, r0 = tid >> 5;
#pragma unroll
    for (int i = 0; i < 4; ++i) {
        int kl = r0 + i * 8;
        int k = k0 + kl;
        int n = n0 + c;
        float v = (k < 512) ? Wx[(size_t)k * 512 + n] : Wh[(size_t)(k - 512) * 512 + n];
        tile[kl][c] = v;
    }
    __syncthreads();
    const int kt = k0 >> 5;
#pragma unroll
    for (int i = 0; i < 4; ++i) {
        int nl = r0 + i * 8;
        int kc = c;
        int n = n0 + nl;
        Wt2[(((size_t)kt * 3 + t) * 512 + n) * 32 + kc] = f2bf(tile[kc][nl]);
    }
}

// main: 256-thr, wave 64x32, block 128x64, BK=32.
// A: fp32 via global_load_lds (addr-preswizzled source, linear dest), 3 slots,
//    converted to bf16 at read time. W: direct global->reg from L2, bb ping-pong.
__global__ __launch_bounds__(THREADS, 2) void augru_main(
    const float* __restrict__ x, const float* __restrict__ h,
    const float* __restrict__ att, const unsigned short* __restrict__ Wt2,
    const float* __restrict__ bu, const float* __restrict__ br,
    const float* __restrict__ bc, float* __restrict__ out) {
    extern __shared__ char smem[];   // 3 x 16 KB
    const int tid = threadIdx.x;
    const int lane = tid & 63;
    const int wid = tid >> 6;   // 0..3
    const int wm = wid >> 1;    // 0..1 -> 64-row half
    const int wn = wid & 1;     // 0..1 -> 32-col half
    const int id = blockIdx.x;
    const int wg = (id & 7) * 256 + (id >> 3);   // XCD-bijective; siblings co-XCD
    const int nb = wg & 7;      // 0..7 -> 64-col block
    const int mb = wg >> 3;     // 0..255
    const int cl = lane & 15;
    const int kg = lane >> 4;

    f32x4 accU[4][2], accR[4][2], accCx[4][2], accCh[4][2];
#pragma unroll
    for (int i = 0; i < 4; ++i)
#pragma unroll
        for (int j = 0; j < 2; ++j) {
            accU[i][j] = (f32x4)(0.f);
            accR[i][j] = (f32x4)(0.f);
            accCx[i][j] = (f32x4)(0.f);
            accCh[i][j] = (f32x4)(0.f);
        }

    // ---- A staging: source-preswizzled global addr, linear LDS dest ----
    // LDS[r][g16] = X[r][g16 ^ (r&7)]  (granule = 16B)
    const int arow_l = lane >> 3;     // 0..7
    const int ag = lane & 7;
    const unsigned aoffBase =
        (unsigned)(mb * 128 + wid * 32 + arow_l) * 2048
        + (unsigned)((ag * 16) ^ (arow_l << 4));
    auto stageA = [&](int slot, int ktn) {
        const char* bp = (ktn < 16) ? (const char*)x : (const char*)h;
        const unsigned ko = (unsigned)(ktn & 15) * 128;
        char* ldsb = smem + slot * ASLOT + wid * 4096;
#pragma unroll
        for (int q = 0; q < 4; ++q)
            load_lds_16B(bp + aoffBase + q * 16384 + ko, ldsb + q * 1024);
    };

    // ---- W direct-to-reg ----
    const char* gW = (const char*)Wt2
        + (size_t)((nb * 64 + wn * 32 + cl) * 64 + kg * 16);
    bf16x8 bbA[3][2], bbB[3][2];
    auto loadW = [&](bf16x8(&dst)[3][2], int ktn) {
        const char* p = gW + (size_t)ktn * 98304;
#pragma unroll
        for (int t = 0; t < 3; ++t)
#pragma unroll
            for (int ni = 0; ni < 2; ++ni)
                dst[t][ni] = *(const bf16x8*)(p + t * 32768 + ni * 1024);
    };

    auto cvt2 = [](float lo, float hi) {
        unsigned int r;
        asm("v_cvt_pk_bf16_f32 %0, %1, %2" : "=v"(r) : "v"(lo), "v"(hi));
        return r;
    };

    // ---- A read + convert: frag k-granules {2kg, 2kg+1} at XOR'd positions ----
    const int s7 = cl & 7;
    const int aRd1 = (wm * 64 + cl) * 128 + (((kg * 2) ^ s7) * 16);
    const int aRd2 = (wm * 64 + cl) * 128 + (((kg * 2 + 1) ^ s7) * 16);
    auto readA = [&](int slot, int mi) {
        const char* p = smem + slot * ASLOT + mi * 2048;
        f32x4 lo = *(const f32x4*)(p + aRd1);
        f32x4 hi = *(const f32x4*)(p + aRd2);
        uint4v q;
        q.x = cvt2(lo[0], lo[1]); q.y = cvt2(lo[2], lo[3]);
        q.z = cvt2(hi[0], hi[1]); q.w = cvt2(hi[2], hi[3]);
        return __builtin_bit_cast(bf16x8, q);
    };

    // prologue: A(0)->slot0, A(1)->slot1 in flight; W(0)->bbA in flight
    stageA(0, 0);
    stageA(1, 1);
    loadW(bbA, 0);

    auto body = [&](int kt, bf16x8(&cur)[3][2], bf16x8(&nxt)[3][2],
                    f32x4(&accC)[4][2]) {
        asm volatile("s_waitcnt vmcnt(0)" ::: "memory");  // A(kt+1) in LDS, W(kt) in regs
        __builtin_amdgcn_s_barrier();
        if (kt + 2 < NKT) stageA((kt + 2) % 3, kt + 2);
        if (kt + 1 < NKT) loadW(nxt, kt + 1);
        __builtin_amdgcn_sched_barrier(0);   // pin prefetch issue before compute
        const int slot = kt % 3;
        bf16x8 a[4];
#pragma unroll
        for (int mi = 0; mi < 4; ++mi)
            a[mi] = readA(slot, mi);
        __builtin_amdgcn_s_setprio(1);
#pragma unroll
        for (int ni = 0; ni < 2; ++ni) {
#pragma unroll
            for (int mi = 0; mi < 4; ++mi)
                accU[mi][ni] = __builtin_amdgcn_mfma_f32_16x16x32_bf16(
                    a[mi], cur[0][ni], accU[mi][ni], 0, 0, 0);
#pragma unroll
            for (int mi = 0; mi < 4; ++mi)
                accR[mi][ni] = __builtin_amdgcn_mfma_f32_16x16x32_bf16(
                    a[mi], cur[1][ni], accR[mi][ni], 0, 0, 0);
#pragma unroll
            for (int mi = 0; mi < 4; ++mi)
                accC[mi][ni] = __builtin_amdgcn_mfma_f32_16x16x32_bf16(
                    a[mi], cur[2][ni], accC[mi][ni], 0, 0, 0);
        }
        __builtin_amdgcn_s_setprio(0);
    };

    body(0, bbA, bbB, accCx);  body(1, bbB, bbA, accCx);
    body(2, bbA, bbB, accCx);  body(3, bbB, bbA, accCx);
    body(4, bbA, bbB, accCx);  body(5, bbB, bbA, accCx);
    body(6, bbA, bbB, accCx);  body(7, bbB, bbA, accCx);
    body(8, bbA, bbB, accCx);  body(9, bbB, bbA, accCx);
    body(10, bbA, bbB, accCx); body(11, bbB, bbA, accCx);
    body(12, bbA, bbB, accCx); body(13, bbB, bbA, accCx);
    body(14, bbA, bbB, accCx); body(15, bbB, bbA, accCx);
    body(16, bbA, bbB, accCh); body(17, bbB, bbA, accCh);
    body(18, bbA, bbB, accCh); body(19, bbB, bbA, accCh);
    body(20, bbA, bbB, accCh); body(21, bbB, bbA, accCh);
    body(22, bbA, bbB, accCh); body(23, bbB, bbA, accCh);
    body(24, bbA, bbB, accCh); body(25, bbB, bbA, accCh);
    body(26, bbA, bbB, accCh); body(27, bbB, bbA, accCh);
    body(28, bbA, bbB, accCh); body(29, bbB, bbA, accCh);
    body(30, bbA, bbB, accCh); body(31, bbB, bbA, accCh);

    // ---- fused epilogue ----
#pragma unroll
    for (int ni = 0; ni < 2; ++ni) {
        const int col = nb * 64 + wn * 32 + ni * 16 + cl;
        const float bU = bu[col];
        const float bR = br[col];
        const float bC = bc[col];
#pragma unroll
        for (int mi = 0; mi < 4; ++mi) {
#pragma unroll
            for (int j = 0; j < 4; ++j) {
                const int row = mb * 128 + wm * 64 + mi * 16 + kg * 4 + j;
                const float up = accU[mi][ni][j] + bU;
                const float rp = accR[mi][ni][j] + bR;
                const float u = 1.f / (1.f + __expf(-up));
                const float r = 1.f / (1.f + __expf(-rp));
                const float cpre = accCx[mi][ni][j] + bC + r * accCh[mi][ni][j];
                const float e = __expf(-2.f * cpre);
                const float cc = (1.f - e) / (1.f + e);   // tanh
                const float aa = att[row];
                const float hv = h[(size_t)row * 512 + col];
                const float u_ = aa * u;
                out[(size_t)row * 512 + col] = (1.f - u_) * hv + u_ * cc;
            }
        }
    }
}

extern "C" void kernel_launch(void* const* d_in, const int* in_sizes, int n_in,
                              void* d_out, int out_size, void* d_ws, size_t ws_size,
                              hipStream_t stream) {
    const float* x    = (const float*)d_in[0];
    const float* h    = (const float*)d_in[1];
    const float* att  = (const float*)d_in[2];
    const float* Wu_x = (const float*)d_in[3];
    const float* bu   = (const float*)d_in[4];
    const float* Wu_h = (const float*)d_in[5];
    const float* Wr_x = (const float*)d_in[6];
    const float* br   = (const float*)d_in[7];
    const float* Wr_h = (const float*)d_in[8];
    const float* Wc_x = (const float*)d_in[9];
    const float* bc   = (const float*)d_in[10];
    const float* Wc_h = (const float*)d_in[11];
    unsigned short* Wt2 = (unsigned short*)d_ws;   // 3 MB
    float* out = (float*)d_out;

    prep_weights<<<dim3(32, 16, 3), 256, 0, stream>>>(Wu_x, Wu_h, Wr_x, Wr_h, Wc_x, Wc_h, Wt2);

    hipFuncSetAttribute((const void*)augru_main,
                        hipFuncAttributeMaxDynamicSharedMemorySize, LDS_TOTAL);
    augru_main<<<dim3(2048), THREADS, LDS_TOTAL, stream>>>(
        x, h, att, Wt2, bu, br, bc, out);
}